// Round 3
// baseline (760.756 us; speedup 1.0000x reference)
//
#include <hip/hip_runtime.h>
#include <math.h>

#define Bn  8
#define SQn 2048
#define SKn 2048
#define Hn  256
#define NHn 4
#define HDn 64
#define SCALEF 0.125f
#define NEGBIG -1e30f

typedef __attribute__((ext_vector_type(4))) float f32x4;
typedef __attribute__((ext_vector_type(4))) unsigned int u32x4;
typedef __attribute__((ext_vector_type(8))) short short8;
typedef unsigned short ushort_t;
typedef unsigned long long ull_t;

__device__ __forceinline__ unsigned short f2bf(float f) {
  unsigned u = __builtin_bit_cast(unsigned, f);
  u += 0x7fffu + ((u >> 16) & 1u);
  return (unsigned short)(u >> 16);
}

__device__ __forceinline__ short8 load8f(const float* p) {
  float4 v0 = *(const float4*)p;
  float4 v1 = *(const float4*)(p + 4);
  short8 r;
  r[0] = (short)f2bf(v0.x); r[1] = (short)f2bf(v0.y);
  r[2] = (short)f2bf(v0.z); r[3] = (short)f2bf(v0.w);
  r[4] = (short)f2bf(v1.x); r[5] = (short)f2bf(v1.y);
  r[6] = (short)f2bf(v1.z); r[7] = (short)f2bf(v1.w);
  return r;
}

__device__ __forceinline__ f32x4 mfma16(short8 a, short8 b, f32x4 c) {
  return __builtin_amdgcn_mfma_f32_16x16x32_bf16(a, b, c, 0, 0, 0);
}

// ---------------------------------------------------------------- mask dtype
__global__ void detect_mask(const unsigned* __restrict__ m, int* __restrict__ flag) {
  if (threadIdx.x == 0) {
    int f = 0;
    for (int i = 0; i < 64; ++i)
      if (m[i] > 1u) f = 1;   // packed bytes -> words like 0x01010101
    flag[0] = f;
  }
}

// ------------------------------------------------- projection GEMM (f32 in)
// Y[m,n] = sum_k X[m,k]*W[n,k] + bias[n];  M=16384, N=K=256
// vtrans==0: Y stored [b][h][s][d] bf16 ;  vtrans==1: Y stored [b][h][d][s]
__global__ __launch_bounds__(256) void proj_kernel(
    const float* __restrict__ X, const float* __restrict__ W,
    const float* __restrict__ bias, unsigned short* __restrict__ Y, int vtrans)
{
  const int m0 = blockIdx.x * 64;
  const int n0 = blockIdx.y * 64;
  const int wv = threadIdx.x >> 6;
  const int l  = threadIdx.x & 63;
  const int lr = l & 15, lg = l >> 4;
  const int mrow = m0 + wv * 16 + lr;

  f32x4 acc[4];
  #pragma unroll
  for (int t = 0; t < 4; ++t) acc[t] = (f32x4){0.f, 0.f, 0.f, 0.f};

  const float* ap = X + (size_t)mrow * Hn + lg * 8;
  for (int k0 = 0; k0 < Hn; k0 += 32) {
    short8 a = load8f(ap + k0);
    #pragma unroll
    for (int t = 0; t < 4; ++t) {
      short8 bb = load8f(W + (size_t)(n0 + t * 16 + lr) * Hn + k0 + lg * 8);
      acc[t] = mfma16(a, bb, acc[t]);
    }
  }

  #pragma unroll
  for (int t = 0; t < 4; ++t) {
    const int n = n0 + t * 16 + lr;
    const float bv = bias[n];
    const int h = n >> 6, d = n & 63;
    if (!vtrans) {
      #pragma unroll
      for (int r = 0; r < 4; ++r) {
        const int m = m0 + wv * 16 + lg * 4 + r;
        const int bb = m >> 11, s = m & 2047;
        size_t idx = (((size_t)bb * NHn + h) * SQn + s) * HDn + d;
        Y[idx] = f2bf(acc[t][r] + bv);
      }
    } else {
      const int m = m0 + wv * 16 + lg * 4;
      const int bb = m >> 11, s = m & 2047;
      ushort4 pk;
      pk.x = f2bf(acc[t][0] + bv); pk.y = f2bf(acc[t][1] + bv);
      pk.z = f2bf(acc[t][2] + bv); pk.w = f2bf(acc[t][3] + bv);
      size_t idx = (((size_t)bb * NHn + h) * HDn + d) * (size_t)SKn + s;
      *(ushort4*)(Y + idx) = pk;
    }
  }
}

// --------------------------------------------------------- fused attention
// One wave owns 16 q-rows x all 2048 k-cols. Swapped mfma(K,Q): D col=lane&15
// is the q row. Permuted K-row placement krA = (lr>>2)*8+(lr&3) makes lane
// (lr,lg) end each 32-col chunk holding S[q0+lr][c+lg*8 .. c+lg*8+7] -- 8
// consecutive cols = float4 x2 attn store AND the PV A-fragment directly.
// No LDS, no barriers, no infinity arithmetic (finite sentinel NEGBIG).
template <int BYTEMASK>
__device__ __forceinline__ void attn_wave(
    int rt, const ushort_t* __restrict__ Qb, const ushort_t* __restrict__ Kb,
    const ushort_t* __restrict__ Vt, const void* __restrict__ maskp,
    float* __restrict__ attn_out, ushort_t* __restrict__ Ob)
{
  const int l  = threadIdx.x & 63;
  const int lr = l & 15, lg = l >> 4;
  const int bh = rt >> 7;                 // 128 row-tiles per (b,h)
  const int q0 = (rt & 127) << 4;
  const int b  = bh >> 2, h = bh & 3;

  const ushort_t* Qh = Qb + (size_t)bh * SQn * HDn;
  const ushort_t* Kh = Kb + (size_t)bh * SKn * HDn;
  const ushort_t* Vh = Vt + (size_t)bh * HDn * SKn;

  short8 qa0 = *(const short8*)(Qh + (q0 + lr) * HDn + lg * 8);
  short8 qa1 = *(const short8*)(Qh + (q0 + lr) * HDn + 32 + lg * 8);

  const int krA = (lr >> 2) * 8 + (lr & 3);   // tileA K-row offset in chunk
  const size_t mrowelem = ((size_t)b * SQn + q0 + lr) * (size_t)SKn;

  // ---- pass 0: stream mask -> 512 bits (one packed word per 4 chunks)
  unsigned mb[16];
  for (int g = 0; g < 16; ++g) {
    unsigned word = 0;
    #pragma unroll
    for (int s = 0; s < 4; ++s) {
      const int c = (g * 4 + s) * 32;
      unsigned bits = 0;
      if (BYTEMASK) {
        const ull_t* rp = (const ull_t*)((const unsigned char*)maskp + mrowelem + c + lg * 8);
        ull_t v = *rp;
        #pragma unroll
        for (int j = 0; j < 8; ++j)
          bits |= (((v >> (8 * j)) & 0xFFull) != 0 ? 1u : 0u) << j;
      } else {
        const u32x4* rp = (const u32x4*)((const int*)maskp + mrowelem + c + lg * 8);
        u32x4 x = rp[0];
        u32x4 y = rp[1];
        #pragma unroll
        for (int j = 0; j < 4; ++j) {
          bits |= (x[j] != 0 ? 1u : 0u) << j;
          bits |= (y[j] != 0 ? 1u : 0u) << (4 + j);
        }
      }
      word |= bits << (s * 8);
    }
    mb[g] = word;
  }

  // ---- pass 1: online masked (max, sum), all finite arithmetic
  float m = NEGBIG, lsum = 0.f;
  for (int g = 0; g < 16; ++g) {
    const unsigned mw = mb[g];
    #pragma unroll
    for (int s = 0; s < 4; ++s) {
      const int c = (g * 4 + s) * 32;
      const ushort_t* kp = Kh + (size_t)(c + krA) * HDn + lg * 8;
      short8 ka0 = *(const short8*)(kp);
      short8 ka1 = *(const short8*)(kp + 32);
      short8 kb0 = *(const short8*)(kp + 4 * HDn);
      short8 kb1 = *(const short8*)(kp + 4 * HDn + 32);
      f32x4 za = (f32x4){0.f, 0.f, 0.f, 0.f}, zb = (f32x4){0.f, 0.f, 0.f, 0.f};
      za = mfma16(ka0, qa0, za); za = mfma16(ka1, qa1, za);
      zb = mfma16(kb0, qa0, zb); zb = mfma16(kb1, qa1, zb);

      const unsigned bits = (mw >> (s * 8)) & 0xFFu;
      float sv[8];
      #pragma unroll
      for (int j = 0; j < 4; ++j) {
        sv[j]     = ((bits >> j) & 1) ? za[j] * SCALEF : NEGBIG;
        sv[4 + j] = ((bits >> (4 + j)) & 1) ? zb[j] * SCALEF : NEGBIG;
      }
      float tm = fmaxf(fmaxf(fmaxf(sv[0], sv[1]), fmaxf(sv[2], sv[3])),
                       fmaxf(fmaxf(sv[4], sv[5]), fmaxf(sv[6], sv[7])));
      float nm = fmaxf(m, tm);
      float acc = 0.f;
      #pragma unroll
      for (int j = 0; j < 8; ++j) acc += __expf(sv[j] - nm);
      lsum = lsum * __expf(m - nm) + acc;
      m = nm;
    }
  }

  // reduce (m, lsum) across the 4 lane-groups sharing row lr (finite math:
  // a lane whose whole subset was masked has m=NEGBIG; its garbage lsum is
  // annihilated by exp(NEGBIG - nm) = 0)
  #pragma unroll
  for (int d = 16; d < 64; d <<= 1) {
    float om = __shfl_xor(m, d);
    float ol = __shfl_xor(lsum, d);
    float nm = fmaxf(m, om);
    lsum = lsum * __expf(m - nm) + ol * __expf(om - nm);
    m = nm;
  }
  const bool rowinf = (m < -1e29f);        // fully-masked row
  const float m2   = rowinf ? 0.f : m;     // keep pass-2 exponents finite
  const float rinv = rowinf ? 0.f : 1.f / lsum;

  // ---- pass 2: recompute scores, write attn (float4 x2), accumulate PV
  float* arow = attn_out + ((size_t)bh * SQn + q0 + lr) * (size_t)SKn;
  f32x4 oacc[4];
  #pragma unroll
  for (int dt = 0; dt < 4; ++dt) oacc[dt] = (f32x4){0.f, 0.f, 0.f, 0.f};

  for (int g = 0; g < 16; ++g) {
    const unsigned mw = mb[g];
    #pragma unroll
    for (int s = 0; s < 4; ++s) {
      const int c = (g * 4 + s) * 32;
      const ushort_t* kp = Kh + (size_t)(c + krA) * HDn + lg * 8;
      short8 ka0 = *(const short8*)(kp);
      short8 ka1 = *(const short8*)(kp + 32);
      short8 kb0 = *(const short8*)(kp + 4 * HDn);
      short8 kb1 = *(const short8*)(kp + 4 * HDn + 32);
      f32x4 za = (f32x4){0.f, 0.f, 0.f, 0.f}, zb = (f32x4){0.f, 0.f, 0.f, 0.f};
      za = mfma16(ka0, qa0, za); za = mfma16(ka1, qa1, za);
      zb = mfma16(kb0, qa0, zb); zb = mfma16(kb1, qa1, zb);

      const unsigned bits = (mw >> (s * 8)) & 0xFFu;
      float w[8];
      #pragma unroll
      for (int j = 0; j < 4; ++j) {
        float ea = __expf(za[j] * SCALEF - m2) * rinv;
        float eb = __expf(zb[j] * SCALEF - m2) * rinv;
        w[j]     = ((bits >> j) & 1) ? ea : 0.f;
        w[4 + j] = ((bits >> (4 + j)) & 1) ? eb : 0.f;
      }
      if (rowinf && c == 0 && lg == 0) w[0] = 1.f;   // one-hot at key 0

      f32x4 wa = (f32x4){w[0], w[1], w[2], w[3]};
      f32x4 wb = (f32x4){w[4], w[5], w[6], w[7]};
      *(f32x4*)(arow + c + lg * 8)     = wa;
      *(f32x4*)(arow + c + lg * 8 + 4) = wb;

      short8 pf;
      #pragma unroll
      for (int j = 0; j < 8; ++j) pf[j] = (short)f2bf(w[j]);
      #pragma unroll
      for (int dt = 0; dt < 4; ++dt) {
        short8 vb = *(const short8*)(Vh + (size_t)(dt * 16 + lr) * SKn + c + lg * 8);
        oacc[dt] = mfma16(pf, vb, oacc[dt]);
      }
    }
  }

  // ---- O store: lane (lr,lg) reg r of tile dt = O[q=lg*4+r][d=dt*16+lr]
  #pragma unroll
  for (int dt = 0; dt < 4; ++dt)
    #pragma unroll
    for (int r = 0; r < 4; ++r)
      Ob[((size_t)b * SQn + q0 + lg * 4 + r) * Hn + h * HDn + dt * 16 + lr] =
          f2bf(oacc[dt][r]);
}

__global__ __launch_bounds__(256) void attn_kernel(
    const ushort_t* __restrict__ Qb, const ushort_t* __restrict__ Kb,
    const ushort_t* __restrict__ Vt, const void* __restrict__ maskp,
    const int* __restrict__ flagp, float* __restrict__ attn_out,
    ushort_t* __restrict__ Ob)
{
  const int wv = threadIdx.x >> 6;
  const int bid = blockIdx.x;
  // XCD-chunked swizzle: 1024 blocks, 8 XCDs -> XCD x gets bh [4x, 4x+4):
  // K+V working set 2 MB < 4 MB per-XCD L2.
  const int swz = (bid & 7) * 128 + (bid >> 3);
  const int rt = swz * 4 + wv;
  if (*flagp) attn_wave<1>(rt, Qb, Kb, Vt, maskp, attn_out, Ob);
  else        attn_wave<0>(rt, Qb, Kb, Vt, maskp, attn_out, Ob);
}

// ------------------------------------------------ output projection (bf16 A)
__global__ __launch_bounds__(256) void oproj_kernel(
    const unsigned short* __restrict__ A, const float* __restrict__ W,
    const float* __restrict__ bias, float* __restrict__ out)
{
  const int m0 = blockIdx.x * 64;
  const int n0 = blockIdx.y * 64;
  const int wv = threadIdx.x >> 6;
  const int l  = threadIdx.x & 63;
  const int lr = l & 15, lg = l >> 4;
  const int mrow = m0 + wv * 16 + lr;

  f32x4 acc[4];
  #pragma unroll
  for (int t = 0; t < 4; ++t) acc[t] = (f32x4){0.f, 0.f, 0.f, 0.f};

  for (int k0 = 0; k0 < Hn; k0 += 32) {
    short8 a = *(const short8*)(A + (size_t)mrow * Hn + k0 + lg * 8);
    #pragma unroll
    for (int t = 0; t < 4; ++t) {
      short8 bb = load8f(W + (size_t)(n0 + t * 16 + lr) * Hn + k0 + lg * 8);
      acc[t] = mfma16(a, bb, acc[t]);
    }
  }
  #pragma unroll
  for (int t = 0; t < 4; ++t) {
    const int n = n0 + t * 16 + lr;
    const float bv = bias[n];
    #pragma unroll
    for (int r = 0; r < 4; ++r) {
      const int m = m0 + wv * 16 + lg * 4 + r;
      out[(size_t)m * Hn + n] = acc[t][r] + bv;
    }
  }
}

extern "C" void kernel_launch(void* const* d_in, const int* in_sizes, int n_in,
                              void* d_out, int out_size, void* d_ws, size_t ws_size,
                              hipStream_t stream) {
  const float* query = (const float*)d_in[0];
  const float* key_  = (const float*)d_in[1];
  const float* value = (const float*)d_in[2];
  const void*  mask  = d_in[3];
  const float* Wq = (const float*)d_in[4];
  const float* bq = (const float*)d_in[5];
  const float* Wk = (const float*)d_in[6];
  const float* bk = (const float*)d_in[7];
  const float* Wv = (const float*)d_in[8];
  const float* bv = (const float*)d_in[9];
  const float* Wo = (const float*)d_in[10];
  const float* bo = (const float*)d_in[11];

  float* out  = (float*)d_out;
  float* attn = out + (size_t)Bn * SQn * Hn;

  char* ws = (char*)d_ws;
  int* flag = (int*)ws;
  unsigned short* Qb = (unsigned short*)(ws + 256);
  unsigned short* Kb = Qb + (size_t)Bn * SQn * Hn;
  unsigned short* Vt = Kb + (size_t)Bn * SKn * Hn;
  unsigned short* Ob = Vt + (size_t)Bn * SKn * Hn;

  detect_mask<<<1, 64, 0, stream>>>((const unsigned*)mask, flag);

  dim3 pg(256, 4);
  proj_kernel<<<pg, 256, 0, stream>>>(query, Wq, bq, Qb, 0);
  proj_kernel<<<pg, 256, 0, stream>>>(key_,  Wk, bk, Kb, 0);
  proj_kernel<<<pg, 256, 0, stream>>>(value, Wv, bv, Vt, 1);

  attn_kernel<<<1024, 256, 0, stream>>>(Qb, Kb, Vt, mask, flag, attn, Ob);

  oproj_kernel<<<dim3(256, 4), 256, 0, stream>>>(Ob, Wo, bo, out);
}

// Round 4
// 627.480 us; speedup vs baseline: 1.2124x; 1.2124x over previous
//
#include <hip/hip_runtime.h>
#include <math.h>

#define Bn  8
#define SQn 2048
#define SKn 2048
#define Hn  256
#define NHn 4
#define HDn 64
#define SCALEF 0.125f
#define NEGBIG -1e30f

typedef __attribute__((ext_vector_type(4))) float f32x4;
typedef __attribute__((ext_vector_type(4))) unsigned int u32x4;
typedef __attribute__((ext_vector_type(8))) short short8;
typedef unsigned short ushort_t;
typedef unsigned long long ull_t;

__device__ __forceinline__ unsigned short f2bf(float f) {
  unsigned u = __builtin_bit_cast(unsigned, f);
  u += 0x7fffu + ((u >> 16) & 1u);
  return (unsigned short)(u >> 16);
}

__device__ __forceinline__ short8 load8f(const float* p) {
  float4 v0 = *(const float4*)p;
  float4 v1 = *(const float4*)(p + 4);
  short8 r;
  r[0] = (short)f2bf(v0.x); r[1] = (short)f2bf(v0.y);
  r[2] = (short)f2bf(v0.z); r[3] = (short)f2bf(v0.w);
  r[4] = (short)f2bf(v1.x); r[5] = (short)f2bf(v1.y);
  r[6] = (short)f2bf(v1.z); r[7] = (short)f2bf(v1.w);
  return r;
}

__device__ __forceinline__ f32x4 mfma16(short8 a, short8 b, f32x4 c) {
  return __builtin_amdgcn_mfma_f32_16x16x32_bf16(a, b, c, 0, 0, 0);
}

// ---------------------------------------------------------------- mask dtype
__global__ void detect_mask(const unsigned* __restrict__ m, int* __restrict__ flag) {
  if (threadIdx.x == 0) {
    int f = 0;
    for (int i = 0; i < 64; ++i)
      if (m[i] > 1u) f = 1;   // packed bytes -> words like 0x01010101
    flag[0] = f;
  }
}

// ------------------------------------------------- projection GEMM (f32 in)
__global__ __launch_bounds__(256) void proj_kernel(
    const float* __restrict__ X, const float* __restrict__ W,
    const float* __restrict__ bias, unsigned short* __restrict__ Y, int vtrans)
{
  const int m0 = blockIdx.x * 64;
  const int n0 = blockIdx.y * 64;
  const int wv = threadIdx.x >> 6;
  const int l  = threadIdx.x & 63;
  const int lr = l & 15, lg = l >> 4;
  const int mrow = m0 + wv * 16 + lr;

  f32x4 acc[4];
  #pragma unroll
  for (int t = 0; t < 4; ++t) acc[t] = (f32x4){0.f, 0.f, 0.f, 0.f};

  const float* ap = X + (size_t)mrow * Hn + lg * 8;
  for (int k0 = 0; k0 < Hn; k0 += 32) {
    short8 a = load8f(ap + k0);
    #pragma unroll
    for (int t = 0; t < 4; ++t) {
      short8 bb = load8f(W + (size_t)(n0 + t * 16 + lr) * Hn + k0 + lg * 8);
      acc[t] = mfma16(a, bb, acc[t]);
    }
  }

  #pragma unroll
  for (int t = 0; t < 4; ++t) {
    const int n = n0 + t * 16 + lr;
    const float bv = bias[n];
    const int h = n >> 6, d = n & 63;
    if (!vtrans) {
      #pragma unroll
      for (int r = 0; r < 4; ++r) {
        const int m = m0 + wv * 16 + lg * 4 + r;
        const int bb = m >> 11, s = m & 2047;
        size_t idx = (((size_t)bb * NHn + h) * SQn + s) * HDn + d;
        Y[idx] = f2bf(acc[t][r] + bv);
      }
    } else {
      const int m = m0 + wv * 16 + lg * 4;
      const int bb = m >> 11, s = m & 2047;
      ushort4 pk;
      pk.x = f2bf(acc[t][0] + bv); pk.y = f2bf(acc[t][1] + bv);
      pk.z = f2bf(acc[t][2] + bv); pk.w = f2bf(acc[t][3] + bv);
      size_t idx = (((size_t)bb * NHn + h) * HDn + d) * (size_t)SKn + s;
      *(ushort4*)(Y + idx) = pk;
    }
  }
}

// --------------------------------------------------------- fused attention
// Block (512 thr, 8 waves) owns one 16-row q-tile. Wave w owns cols
// [256w, 256w+256): 8 chunks of 32. Swapped mfma(K,Q) + krA permutation
// (R3-proven): lane (lr,lg) ends each chunk with S[q0+lr][c+lg*8..+7].
// Pass 1: per-wave online (max,sum) -> shfl reduce -> LDS combine across
// 8 waves. Pass 2: recompute QK (K in L1/L2), write attn float4 x2,
// accumulate PV partial O; LDS-reduce O across waves. Finite math only.
template <int BYTEMASK>
__device__ __forceinline__ void attn_block(
    int rt, const ushort_t* __restrict__ Qb, const ushort_t* __restrict__ Kb,
    const ushort_t* __restrict__ Vt, const void* __restrict__ maskp,
    float* __restrict__ attn_out, ushort_t* __restrict__ Ob)
{
  __shared__ float red[8][16][2];
  __shared__ float Opart[8][16][66];   // padded stride 66 vs 64: kills 4-way bank conflict

  const int wv = threadIdx.x >> 6;
  const int l  = threadIdx.x & 63;
  const int lr = l & 15, lg = l >> 4;
  const int bh = rt >> 7;
  const int q0 = (rt & 127) << 4;
  const int b  = bh >> 2, h = bh & 3;
  const int colbase = wv * 256;

  const ushort_t* Qh = Qb + (size_t)bh * SQn * HDn;
  const ushort_t* Kh = Kb + (size_t)bh * SKn * HDn;
  const ushort_t* Vh = Vt + (size_t)bh * HDn * SKn;

  short8 qa0 = *(const short8*)(Qh + (q0 + lr) * HDn + lg * 8);
  short8 qa1 = *(const short8*)(Qh + (q0 + lr) * HDn + 32 + lg * 8);

  const int krA = (lr >> 2) * 8 + (lr & 3);
  const size_t mrowelem = ((size_t)b * SQn + q0 + lr) * (size_t)SKn;

  // ---- pass 0: mask bits for this wave's 8 chunks (8 bits per chunk)
  unsigned mb[2];
  #pragma unroll
  for (int g = 0; g < 2; ++g) {
    unsigned word = 0;
    #pragma unroll
    for (int s = 0; s < 4; ++s) {
      const int c = colbase + (g * 4 + s) * 32;
      unsigned bits = 0;
      if (BYTEMASK) {
        ull_t v = *(const ull_t*)((const unsigned char*)maskp + mrowelem + c + lg * 8);
        #pragma unroll
        for (int j = 0; j < 8; ++j)
          bits |= (((v >> (8 * j)) & 0xFFull) != 0 ? 1u : 0u) << j;
      } else {
        const u32x4* rp = (const u32x4*)((const int*)maskp + mrowelem + c + lg * 8);
        u32x4 x = rp[0];
        u32x4 y = rp[1];
        #pragma unroll
        for (int j = 0; j < 4; ++j) {
          bits |= (x[j] != 0 ? 1u : 0u) << j;
          bits |= (y[j] != 0 ? 1u : 0u) << (4 + j);
        }
      }
      word |= bits << (s * 8);
    }
    mb[g] = word;
  }

  // ---- pass 1: online masked (max, sum) over this wave's 256 cols
  float m = NEGBIG, lsum = 0.f;
  #pragma unroll 2
  for (int s8 = 0; s8 < 8; ++s8) {
    const int c = colbase + s8 * 32;
    const ushort_t* kp = Kh + (size_t)(c + krA) * HDn + lg * 8;
    short8 ka0 = *(const short8*)(kp);
    short8 ka1 = *(const short8*)(kp + 32);
    short8 kb0 = *(const short8*)(kp + 4 * HDn);
    short8 kb1 = *(const short8*)(kp + 4 * HDn + 32);
    f32x4 za = (f32x4){0.f, 0.f, 0.f, 0.f}, zb = (f32x4){0.f, 0.f, 0.f, 0.f};
    za = mfma16(ka0, qa0, za); za = mfma16(ka1, qa1, za);
    zb = mfma16(kb0, qa0, zb); zb = mfma16(kb1, qa1, zb);

    const unsigned bits = (mb[s8 >> 2] >> ((s8 & 3) * 8)) & 0xFFu;
    float sv[8];
    #pragma unroll
    for (int j = 0; j < 4; ++j) {
      sv[j]     = ((bits >> j) & 1) ? za[j] * SCALEF : NEGBIG;
      sv[4 + j] = ((bits >> (4 + j)) & 1) ? zb[j] * SCALEF : NEGBIG;
    }
    float tm = fmaxf(fmaxf(fmaxf(sv[0], sv[1]), fmaxf(sv[2], sv[3])),
                     fmaxf(fmaxf(sv[4], sv[5]), fmaxf(sv[6], sv[7])));
    float nm = fmaxf(m, tm);
    float acc = 0.f;
    #pragma unroll
    for (int j = 0; j < 8; ++j) acc += __expf(sv[j] - nm);
    lsum = lsum * __expf(m - nm) + acc;
    m = nm;
  }

  // per-wave reduce across the 4 lane-groups sharing row lr
  #pragma unroll
  for (int d = 16; d < 64; d <<= 1) {
    float om = __shfl_xor(m, d);
    float ol = __shfl_xor(lsum, d);
    float nm = fmaxf(m, om);
    lsum = lsum * __expf(m - nm) + ol * __expf(om - nm);
    m = nm;
  }
  if (l < 16) { red[wv][lr][0] = m; red[wv][lr][1] = lsum; }
  __syncthreads();

  // combine 8 waves' (m, lsum) for row lr (every lane computes its row's)
  float gm = NEGBIG, gl = 0.f;
  #pragma unroll
  for (int w = 0; w < 8; ++w) {
    float rm = red[w][lr][0], rl = red[w][lr][1];
    float nm = fmaxf(gm, rm);
    gl = gl * __expf(gm - nm) + rl * __expf(rm - nm);
    gm = nm;
  }
  const bool rowinf = (gm < -1e29f);      // fully-masked row
  const float m2   = rowinf ? 0.f : gm;
  const float rinv = rowinf ? 0.f : 1.f / gl;

  // ---- pass 2: recompute scores, write attn, accumulate PV partial O
  float* arow = attn_out + ((size_t)bh * SQn + q0 + lr) * (size_t)SKn;
  f32x4 oacc[4];
  #pragma unroll
  for (int dt = 0; dt < 4; ++dt) oacc[dt] = (f32x4){0.f, 0.f, 0.f, 0.f};

  #pragma unroll 2
  for (int s8 = 0; s8 < 8; ++s8) {
    const int c = colbase + s8 * 32;
    const ushort_t* kp = Kh + (size_t)(c + krA) * HDn + lg * 8;
    short8 ka0 = *(const short8*)(kp);
    short8 ka1 = *(const short8*)(kp + 32);
    short8 kb0 = *(const short8*)(kp + 4 * HDn);
    short8 kb1 = *(const short8*)(kp + 4 * HDn + 32);
    f32x4 za = (f32x4){0.f, 0.f, 0.f, 0.f}, zb = (f32x4){0.f, 0.f, 0.f, 0.f};
    za = mfma16(ka0, qa0, za); za = mfma16(ka1, qa1, za);
    zb = mfma16(kb0, qa0, zb); zb = mfma16(kb1, qa1, zb);

    const unsigned bits = (mb[s8 >> 2] >> ((s8 & 3) * 8)) & 0xFFu;
    float w[8];
    #pragma unroll
    for (int j = 0; j < 4; ++j) {
      float ea = __expf(za[j] * SCALEF - m2) * rinv;
      float eb = __expf(zb[j] * SCALEF - m2) * rinv;
      w[j]     = ((bits >> j) & 1) ? ea : 0.f;
      w[4 + j] = ((bits >> (4 + j)) & 1) ? eb : 0.f;
    }
    if (rowinf && c == 0 && lg == 0) w[0] = 1.f;   // one-hot at key 0 (wave 0 only)

    *(f32x4*)(arow + c + lg * 8)     = (f32x4){w[0], w[1], w[2], w[3]};
    *(f32x4*)(arow + c + lg * 8 + 4) = (f32x4){w[4], w[5], w[6], w[7]};

    short8 pf;
    #pragma unroll
    for (int j = 0; j < 8; ++j) pf[j] = (short)f2bf(w[j]);
    #pragma unroll
    for (int dt = 0; dt < 4; ++dt) {
      short8 vb = *(const short8*)(Vh + (size_t)(dt * 16 + lr) * SKn + c + lg * 8);
      oacc[dt] = mfma16(pf, vb, oacc[dt]);
    }
  }

  // ---- cross-wave O reduce. Partial layout: O[q=lg*4+r][d=dt*16+lr]
  #pragma unroll
  for (int dt = 0; dt < 4; ++dt)
    #pragma unroll
    for (int r = 0; r < 4; ++r)
      Opart[wv][lg * 4 + r][dt * 16 + lr] = oacc[dt][r];
  __syncthreads();

  #pragma unroll
  for (int e = threadIdx.x; e < 1024; e += 512) {
    const int row = e >> 6, d = e & 63;
    float s = 0.f;
    #pragma unroll
    for (int w = 0; w < 8; ++w) s += Opart[w][row][d];
    Ob[((size_t)b * SQn + q0 + row) * Hn + h * HDn + d] = f2bf(s);
  }
}

__global__ __launch_bounds__(512) void attn_kernel(
    const ushort_t* __restrict__ Qb, const ushort_t* __restrict__ Kb,
    const ushort_t* __restrict__ Vt, const void* __restrict__ maskp,
    const int* __restrict__ flagp, float* __restrict__ attn_out,
    ushort_t* __restrict__ Ob)
{
  const int bid = blockIdx.x;
  // Bijective XCD-chunked swizzle: 4096 blocks, 8 XCDs, 512 blocks/XCD ->
  // XCD x serves 4 consecutive bh: K+V working set 2 MB < 4 MB L2.
  const int swz = (bid & 7) * 512 + (bid >> 3);
  if (*flagp) attn_block<1>(swz, Qb, Kb, Vt, maskp, attn_out, Ob);
  else        attn_block<0>(swz, Qb, Kb, Vt, maskp, attn_out, Ob);
}

// ------------------------------------------------ output projection (bf16 A)
__global__ __launch_bounds__(256) void oproj_kernel(
    const unsigned short* __restrict__ A, const float* __restrict__ W,
    const float* __restrict__ bias, float* __restrict__ out)
{
  const int m0 = blockIdx.x * 64;
  const int n0 = blockIdx.y * 64;
  const int wv = threadIdx.x >> 6;
  const int l  = threadIdx.x & 63;
  const int lr = l & 15, lg = l >> 4;
  const int mrow = m0 + wv * 16 + lr;

  f32x4 acc[4];
  #pragma unroll
  for (int t = 0; t < 4; ++t) acc[t] = (f32x4){0.f, 0.f, 0.f, 0.f};

  for (int k0 = 0; k0 < Hn; k0 += 32) {
    short8 a = *(const short8*)(A + (size_t)mrow * Hn + k0 + lg * 8);
    #pragma unroll
    for (int t = 0; t < 4; ++t) {
      short8 bb = load8f(W + (size_t)(n0 + t * 16 + lr) * Hn + k0 + lg * 8);
      acc[t] = mfma16(a, bb, acc[t]);
    }
  }
  #pragma unroll
  for (int t = 0; t < 4; ++t) {
    const int n = n0 + t * 16 + lr;
    const float bv = bias[n];
    #pragma unroll
    for (int r = 0; r < 4; ++r) {
      const int m = m0 + wv * 16 + lg * 4 + r;
      out[(size_t)m * Hn + n] = acc[t][r] + bv;
    }
  }
}

extern "C" void kernel_launch(void* const* d_in, const int* in_sizes, int n_in,
                              void* d_out, int out_size, void* d_ws, size_t ws_size,
                              hipStream_t stream) {
  const float* query = (const float*)d_in[0];
  const float* key_  = (const float*)d_in[1];
  const float* value = (const float*)d_in[2];
  const void*  mask  = d_in[3];
  const float* Wq = (const float*)d_in[4];
  const float* bq = (const float*)d_in[5];
  const float* Wk = (const float*)d_in[6];
  const float* bk = (const float*)d_in[7];
  const float* Wv = (const float*)d_in[8];
  const float* bv = (const float*)d_in[9];
  const float* Wo = (const float*)d_in[10];
  const float* bo = (const float*)d_in[11];

  float* out  = (float*)d_out;
  float* attn = out + (size_t)Bn * SQn * Hn;

  char* ws = (char*)d_ws;
  int* flag = (int*)ws;
  unsigned short* Qb = (unsigned short*)(ws + 256);
  unsigned short* Kb = Qb + (size_t)Bn * SQn * Hn;
  unsigned short* Vt = Kb + (size_t)Bn * SKn * Hn;
  unsigned short* Ob = Vt + (size_t)Bn * SKn * Hn;

  detect_mask<<<1, 64, 0, stream>>>((const unsigned*)mask, flag);

  dim3 pg(256, 4);
  proj_kernel<<<pg, 256, 0, stream>>>(query, Wq, bq, Qb, 0);
  proj_kernel<<<pg, 256, 0, stream>>>(key_,  Wk, bk, Kb, 0);
  proj_kernel<<<pg, 256, 0, stream>>>(value, Wv, bv, Vt, 1);

  attn_kernel<<<4096, 512, 0, stream>>>(Qb, Kb, Vt, mask, flag, attn, Ob);

  oproj_kernel<<<dim3(256, 4), 256, 0, stream>>>(Ob, Wo, bo, out);
}